// Round 6
// baseline (18613.702 us; speedup 1.0000x reference)
//
#include <hip/hip_runtime.h>

// EA-LSTM fused kernel, v6.1: full fp32, 4-CU teams, sub-cap register residency.
//
// v4/v5: PASSED (0.5) but 18.3 ms; VGPR_Count pinned at 128 for both
// __launch_bounds__(512,2) and (512,1) -> allocator targets 4 waves/EU on
// its own heuristic; weight arrays >128 regs spill and get REMATERIALIZED
// from global every step (FETCH 17-19 GB = whole runtime). v6 designs under
// the cap. Round-5 run died at container level (infra or hang) -> v6.1
// hardens: bounded spins (deadlock -> terminating wrong answer, not a dead
// container), s_sleep in spin loops, ws footprint packed into 16 KB (the
// envelope v4/v5 proved), amdgpu_waves_per_eu(2,2) to pin the allocator at
// our real occupancy (8 waves/block, 1 block/CU = 2/EU -> 256-VGPR budget).
//
// Layout: 64 teams x 4 roles; block = role*64 + team -> partners
// {team,+64,+128,+192} all same XCD (== mod 8). Role owns 64 output units
// (cols {64r+i, 256+64r+i, 512+64r+i}). Thread (kq8=t>>6, i=t&63) holds
// rows [32*kq8,+32) x f,o cols = 64 fp32 regs (+acc ~= 125 total).
// g-gate weights in LDS (64 KB float4, lane-dense), W_ih quarter (24 KB),
// partials (24 KB) -> 117 KB LDS, unspillable. Team processes 4 batch
// elements -> weights reused 4x; 432 FMA/thread/step (262 us @ 157 TF
// fp32 roofline for the whole problem).
//
// Per-step cross-CU h-exchange: gate lanes write h to hn_out (required
// output anyway); wave kq8 consumes rows produced by role p=kq8>>1 - own
// rows from LDS, partner rows from hn_out after agent-scope acquire on
// p's monotone step-flag in d_ws (fc partials ride in the same 64B flag
// line, stored before the release). Startup rendezvous through cn_out row
// 364 (harness memsets d_out pre-launch; those words are legitimately
// written only at s=364, after all rendezvous reads) -> stale-ws/replay
// safe: each role zeroes its ws flag BEFORE posting its ready magic.

#define BB 256
#define SS 365
#define FD 32
#define FS 27
#define HH 256
#define NT 512
typedef unsigned int u32;

#define AGENT __HIP_MEMORY_SCOPE_AGENT

// bounded spin: first check is sleep-free (common case: partner already
// ahead); bound converts any deadlock into a terminating wrong answer.
#define SPIN_UNTIL(COND) \
    { int _it = 0; while (!(COND) && _it < (1 << 26)) { __builtin_amdgcn_s_sleep(1); ++_it; } }

struct Smem {
    __align__(16) float4 wg4[8][8][64];    // 64 KB  g-gate weights [kq8][j4][i]
    __align__(16) float wih[FD][3][64];    // 24 KB  W_ih quarter
    __align__(16) float part[4][3][8][64]; // 24 KB  partials [elem][gate][kq8][i]
    __align__(16) float hbuf[4][64];       // 1 KB   own-slice h per elem
    __align__(16) float xbuf[2][4][FD];    // 1 KB   x rows, double-buffered
    float outp[4];                         // per-elem fc wave sums
};

// 4 rows x 3 gates x 4 elems of MACs; wf/wo from regs, g from LDS float4.
#define HGEMV(SRC) \
    _Pragma("unroll") \
    for (int j4 = 0; j4 < 8; ++j4) { \
        const float4 G = sm.wg4[kq8][j4][i]; \
        _Pragma("unroll") \
        for (int e = 0; e < 4; ++e) { \
            const float4 H = (SRC); \
            ac0[e] = fmaf(H.x, wf[4*j4+0], ac0[e]); \
            ac0[e] = fmaf(H.y, wf[4*j4+1], ac0[e]); \
            ac0[e] = fmaf(H.z, wf[4*j4+2], ac0[e]); \
            ac0[e] = fmaf(H.w, wf[4*j4+3], ac0[e]); \
            ac1[e] = fmaf(H.x, wo[4*j4+0], ac1[e]); \
            ac1[e] = fmaf(H.y, wo[4*j4+1], ac1[e]); \
            ac1[e] = fmaf(H.z, wo[4*j4+2], ac1[e]); \
            ac1[e] = fmaf(H.w, wo[4*j4+3], ac1[e]); \
            ac2[e] = fmaf(H.x, G.x, ac2[e]); \
            ac2[e] = fmaf(H.y, G.y, ac2[e]); \
            ac2[e] = fmaf(H.z, G.z, ac2[e]); \
            ac2[e] = fmaf(H.w, G.w, ac2[e]); \
        } \
    }

__global__ __launch_bounds__(NT)
__attribute__((amdgpu_waves_per_eu(2, 2)))
void ealstm_kernel(
    const float* __restrict__ x_d, const float* __restrict__ x_s,
    const float* __restrict__ W_ih, const float* __restrict__ W_hh,
    const float* __restrict__ W_sh, const float* __restrict__ bias,
    const float* __restrict__ bias_s, const float* __restrict__ W_fc,
    const float* __restrict__ b_fc, float* __restrict__ d_out,
    u32* __restrict__ ws)
{
    extern __shared__ __align__(16) unsigned char smem_raw[];
    Smem& sm = *reinterpret_cast<Smem*>(smem_raw);

    const int t = threadIdx.x;
    const int blk = blockIdx.x;
    const int role = blk >> 6;          // 0..3 : owns units [64*role, +64)
    const int team = blk & 63;          // 0..63: elems {team,+64,+128,+192}
    const int kq8 = t >> 6;             // wave id: consumes h rows [32*kq8,+32)
    const int i   = t & 63;
    const int p   = kq8 >> 1;           // role that produces those h rows

    float* __restrict__ out_fc = d_out;                      // [B,S,1]
    float* __restrict__ hn_out = d_out + (size_t)BB * SS;    // [B,S,H]
    float* __restrict__ cn_out = hn_out + (size_t)BB * SS * HH;

    // ws: 64 teams x 4 roles x 16 u32 (64B line) = 16 KB total.
    // line layout: u32[0] = monotone step flag; u32[4..11] = fc partials
    // (2 parity buffers x 4 elems), stored BEFORE the flag's release-store.
    u32* flags   = ws + (size_t)team * 64;
    u32* flag_my = flags + role * 16;
    float* fcp_my = (float*)(flag_my + 4);

    // ---- register-resident weights: rows [32*kq8,+32) x cols f,o
    float wf[32], wo[32];
    {
        const float* basef = W_hh + (size_t)(32 * kq8) * 768 + 64 * role + i;
#pragma unroll
        for (int j = 0; j < 32; ++j) {
            wf[j] = basef[(size_t)j * 768];
            wo[j] = basef[(size_t)j * 768 + 256];
        }
        // g-gate rows -> LDS float4 (rows 4j4..4j4+3 for col 512+64r+i)
#pragma unroll
        for (int j4 = 0; j4 < 8; ++j4) {
            const float* pg = basef + (size_t)(4 * j4) * 768 + 512;
            sm.wg4[kq8][j4][i] = make_float4(pg[0], pg[768], pg[2 * 768], pg[3 * 768]);
        }
    }
    // ---- W_ih quarter -> LDS
    for (int idx = t; idx < FD * 3 * 64; idx += NT) {
        const int k = idx / 192, rem = idx - k * 192;
        const int g = rem >> 6, cc = rem & 63;
        sm.wih[k][g][cc] = W_ih[(size_t)k * 768 + g * 256 + 64 * role + cc];
    }
    // ---- x row 0 for the 4 elements
    if (t < 128) {
        const int e = t >> 5, xf = t & 31;
        sm.xbuf[0][e][xf] = x_d[(size_t)(team + 64 * e) * SS * FD + xf];
    }
    // ---- gate-lane constants/state (t<256: elem e=t>>6, unit 64*role+(t&63))
    float c_state = 0.f, igv = 0.f, bfv = 0.f, bov = 0.f, bgv = 0.f, wfcv = 0.f;
    if (t < 256) {
        const int e = t >> 6, ii = t & 63, u = 64 * role + ii;
        const int eb = team + 64 * e;
        float accs = bias_s[u];
        for (int k = 0; k < FS; ++k)
            accs = fmaf(x_s[(size_t)eb * FS + k], W_sh[(size_t)k * HH + u], accs);
        igv = 1.f / (1.f + __expf(-accs));
        bfv = bias[u]; bov = bias[HH + u]; bgv = bias[2 * HH + u];
        wfcv = W_fc[u];
        sm.hbuf[e][ii] = 0.f;                      // h0 = 0
    }
    const float bfc = b_fc[0];

    // ---- startup rendezvous (zero own ws flag BEFORE posting ready magic)
    u32* rdyrow = (u32*)(cn_out + ((size_t)team * SS + (SS - 1)) * HH);
    if (t == 0) {
        __hip_atomic_store(flag_my, 0u, __ATOMIC_RELAXED, AGENT);
        __threadfence();
        __hip_atomic_store(rdyrow + 64 * role, 0x3F800000u, __ATOMIC_RELEASE, AGENT);
        for (int r = 0; r < 4; ++r)
            if (r != role)
                SPIN_UNTIL(__hip_atomic_load(rdyrow + 64 * r, __ATOMIC_ACQUIRE, AGENT)
                           == 0x3F800000u)
    }
    __syncthreads();

    const size_t ESTR = (size_t)64 * SS * HH;   // elem stride in hn_out

    for (int s = 0; s < SS; ++s) {
        const int par = s & 1;
        // ---- publish step s-1: h rows already in hn_out (drained by barrier);
        //      fc partials into our flag line, then bump the monotone flag.
        if (t == 0 && s > 0) {
            const int pp = (s - 1) & 1;
#pragma unroll
            for (int e = 0; e < 4; ++e) fcp_my[pp * 4 + e] = sm.outp[e];
            __threadfence();
            __hip_atomic_store(flag_my, (u32)s, __ATOMIC_RELEASE, AGENT);
        }
        // ---- x prefetch for s+1 (waves 4-5; lands before the mid barrier)
        float xpre = 0.f; const int xi = t - 256;
        if (xi >= 0 && xi < 128) {
            const int xe = xi >> 5, xf = xi & 31;
            const int sn = (s + 1 < SS) ? s + 1 : SS - 1;
            xpre = x_d[((size_t)(team + 64 * xe) * SS + sn) * FD + xf];
        }
        // ---- x-projection partial (W_ih rows [4*kq8, +4))
        float ac0[4] = {0.f, 0.f, 0.f, 0.f};
        float ac1[4] = {0.f, 0.f, 0.f, 0.f};
        float ac2[4] = {0.f, 0.f, 0.f, 0.f};
        {
            const int x0 = 4 * kq8;
#pragma unroll
            for (int j = 0; j < 4; ++j) {
                const float w0 = sm.wih[x0 + j][0][i];
                const float w1 = sm.wih[x0 + j][1][i];
                const float w2 = sm.wih[x0 + j][2][i];
#pragma unroll
                for (int e = 0; e < 4; ++e) {
                    const float xv = sm.xbuf[par][e][x0 + j];
                    ac0[e] = fmaf(xv, w0, ac0[e]);
                    ac1[e] = fmaf(xv, w1, ac1[e]);
                    ac2[e] = fmaf(xv, w2, ac2[e]);
                }
            }
        }
        // ---- deferred fc head write for s-1 (role 0, wave-4 lane 0)
        if (role == 0 && t == 256 && s > 0) {
            const int pp = (s - 1) & 1;
            for (int r = 1; r < 4; ++r)
                SPIN_UNTIL((int)__hip_atomic_load(flags + r * 16, __ATOMIC_ACQUIRE,
                                                  AGENT) >= s)
#pragma unroll
            for (int e = 0; e < 4; ++e) {
                float v = sm.outp[e] + bfc;
                for (int r = 1; r < 4; ++r)
                    v += ((const float*)(flags + r * 16 + 4))[pp * 4 + e];
                out_fc[(size_t)(team + 64 * e) * SS + (s - 1)] = v;
            }
        }
        // ---- h @ W_hh (skip at s=0: h=0). Wave-uniform source select.
        if (s > 0) {
            if (p == role) {
                const int hoff = 32 * (kq8 & 1);
                HGEMV(reinterpret_cast<const float4*>(&sm.hbuf[e][hoff])[j4])
            } else {
                SPIN_UNTIL((int)__hip_atomic_load(flags + p * 16, __ATOMIC_ACQUIRE,
                                                  AGENT) >= s)
                const float* hpb = hn_out + ((size_t)team * SS + (s - 1)) * HH + 32 * kq8;
                HGEMV(reinterpret_cast<const float4*>(hpb + e * ESTR)[j4])
            }
        }
        // ---- partials + land prefetched x
#pragma unroll
        for (int e = 0; e < 4; ++e) {
            sm.part[e][0][kq8][i] = ac0[e];
            sm.part[e][1][kq8][i] = ac1[e];
            sm.part[e][2][kq8][i] = ac2[e];
        }
        if (xi >= 0 && xi < 128) sm.xbuf[par ^ 1][xi >> 5][xi & 31] = xpre;
        __syncthreads();

        // ---- gate phase (t<256: elem e, unit 64*role+ii)
        if (t < 256) {
            const int e = t >> 6, ii = t & 63;
            float f = bfv, o = bov, g = bgv;
#pragma unroll
            for (int q = 0; q < 8; ++q) {
                f += sm.part[e][0][q][ii];
                o += sm.part[e][1][q][ii];
                g += sm.part[e][2][q][ii];
            }
            const float sf = 1.f / (1.f + __expf(-f));
            const float so = 1.f / (1.f + __expf(-o));
            const float tg = 1.f - 2.f / (1.f + __expf(2.f * g));   // safe tanh
            c_state = sf * c_state + igv * tg;
            const float tc = 1.f - 2.f / (1.f + __expf(2.f * c_state));
            const float h1 = so * tc;
            sm.hbuf[e][ii] = h1;
            const size_t oidx = ((size_t)(team + 64 * e) * SS + s) * HH + 64 * role + ii;
            hn_out[oidx] = h1;
            cn_out[oidx] = c_state;
            float psum = h1 * wfcv;
#pragma unroll
            for (int d = 32; d > 0; d >>= 1) psum += __shfl_down(psum, d);
            if (ii == 0) sm.outp[e] = psum;
        }
        __syncthreads();   // drains hn/cn stores before next step's publish
    }

    // ---- epilogue: final publish + fc row 364
    {
        const int pp = (SS - 1) & 1;
        if (t == 0) {
#pragma unroll
            for (int e = 0; e < 4; ++e) fcp_my[pp * 4 + e] = sm.outp[e];
            __threadfence();
            __hip_atomic_store(flag_my, (u32)SS, __ATOMIC_RELEASE, AGENT);
        }
        if (role == 0 && t == 256) {
            for (int r = 1; r < 4; ++r)
                SPIN_UNTIL((int)__hip_atomic_load(flags + r * 16, __ATOMIC_ACQUIRE,
                                                  AGENT) >= SS)
#pragma unroll
            for (int e = 0; e < 4; ++e) {
                float v = sm.outp[e] + bfc;
                for (int r = 1; r < 4; ++r)
                    v += ((const float*)(flags + r * 16 + 4))[pp * 4 + e];
                out_fc[(size_t)(team + 64 * e) * SS + (SS - 1)] = v;
            }
        }
    }
}

extern "C" void kernel_launch(void* const* d_in, const int* in_sizes, int n_in,
                              void* d_out, int out_size, void* d_ws, size_t ws_size,
                              hipStream_t stream) {
    const float* x_d    = (const float*)d_in[0];
    const float* x_s    = (const float*)d_in[1];
    const float* W_ih   = (const float*)d_in[2];
    const float* W_hh   = (const float*)d_in[3];
    const float* W_sh   = (const float*)d_in[4];
    const float* bias   = (const float*)d_in[5];
    const float* bias_s = (const float*)d_in[6];
    const float* W_fc   = (const float*)d_in[7];
    const float* b_fc   = (const float*)d_in[8];

    static bool smem_set = false;
    if (!smem_set) {
        hipFuncSetAttribute((const void*)ealstm_kernel,
                            hipFuncAttributeMaxDynamicSharedMemorySize,
                            (int)sizeof(Smem));
        smem_set = true;
    }

    ealstm_kernel<<<dim3(BB), dim3(NT), sizeof(Smem), stream>>>(
        x_d, x_s, W_ih, W_hh, W_sh, bias, bias_s, W_fc, b_fc,
        (float*)d_out, (u32*)d_ws);
}

// Round 7
// 8576.830 us; speedup vs baseline: 2.1702x; 2.1702x over previous
//
#include <hip/hip_runtime.h>

// EA-LSTM fused kernel, v7: full fp32, 4-CU teams, cache-op-free sync.
//
// v4/v5/v6.1 post-mortem: three different register/LDS layouts, identical
// sync protocol, identical ~50 us/step. v6.1 fit under the 128-VGPR cap
// (no spill possible) yet FETCH stayed at 15.9 GB with ~55 MB of real
// input traffic -> the acquire/release+threadfence protocol is the cost:
// agent scope on gfx950 must bridge non-coherent per-XCD L2s, so acquire
// spins emit L2 INVALIDATES and releases L2 WRITEBACKS. 6 waves/CU
// spinning = perpetual L2-invalidation storm: every step re-fetches
// everything from HBM and each handshake costs tens of us.
//
// v7: zero cache-maintenance ops in the loop. All cross-CU communication
// uses RELAXED agent-scope atomics (sc-routed to the device coherence
// point -> correct regardless of XCD placement, Guideline 16):
//  - gate lanes store h to hn_out via relaxed atomic stores (output anyway);
//  - __syncthreads()'s built-in vmcnt(0) drain is the release ordering;
//    t==0 then bumps a monotone step flag (relaxed atomic store);
//  - consumer waves poll the flag (relaxed atomic load, 1 dword, no inv),
//    then lane-parallel fetch the 128 partner-h dwords (relaxed atomic
//    loads), bounce through per-wave LDS scratch, GEMV from uniform float4.
//  - fc partials ride the flag line as relaxed atomics; an explicit
//    s_waitcnt vmcnt(0) orders them before the flag bump.
//
// Layout (unchanged from v6.1): 64 teams x 4 roles; block = role*64+team.
// Role owns 64 output units (cols {64r+i, 256+64r+i, 512+64r+i}).
// Thread (kq8=t>>6, i=t&63) holds rows [32*kq8,+32) x f,o cols = 64 fp32
// regs (~125 total, fits the observed 128 allocation). g-gate weights in
// LDS (64 KB float4), W_ih quarter (24 KB), partials (24 KB), h-exchange
// scratch (4 KB) -> 118 KB LDS -> 1 block/CU, all 256 blocks co-resident.
// Team processes 4 batch elements -> 432 FMA/thread/step.

#define BB 256
#define SS 365
#define FD 32
#define FS 27
#define HH 256
#define NT 512
typedef unsigned int u32;

#define AGENT __HIP_MEMORY_SCOPE_AGENT

// bounded spin, relaxed loads only (no cache ops); memory clobber at exit
// stops the compiler hoisting dependent loads above the loop. Bound turns
// any deadlock into a terminating wrong answer instead of a dead container.
#define SPIN_UNTIL(COND) \
    { int _it = 0; while (!(COND) && _it < (1 << 26)) { __builtin_amdgcn_s_sleep(1); ++_it; } \
      asm volatile("" ::: "memory"); }

struct Smem {
    __align__(16) float4 wg4[8][8][64];    // 64 KB  g-gate weights [kq8][j4][i]
    __align__(16) float wih[FD][3][64];    // 24 KB  W_ih quarter
    __align__(16) float part[4][3][8][64]; // 24 KB  partials [elem][gate][kq8][i]
    __align__(16) float hbuf[4][64];       // 1 KB   own-slice h per elem
    __align__(16) float hxch[8][128];      // 4 KB   per-wave partner-h bounce
    __align__(16) float xbuf[2][4][FD];    // 1 KB   x rows, double-buffered
    float outp[4];                         // per-elem fc wave sums
};

// 4 rows x 3 gates x 4 elems of MACs; wf/wo from regs, g from LDS float4.
#define HGEMV(SRC) \
    _Pragma("unroll") \
    for (int j4 = 0; j4 < 8; ++j4) { \
        const float4 G = sm.wg4[kq8][j4][i]; \
        _Pragma("unroll") \
        for (int e = 0; e < 4; ++e) { \
            const float4 H = (SRC); \
            ac0[e] = fmaf(H.x, wf[4*j4+0], ac0[e]); \
            ac0[e] = fmaf(H.y, wf[4*j4+1], ac0[e]); \
            ac0[e] = fmaf(H.z, wf[4*j4+2], ac0[e]); \
            ac0[e] = fmaf(H.w, wf[4*j4+3], ac0[e]); \
            ac1[e] = fmaf(H.x, wo[4*j4+0], ac1[e]); \
            ac1[e] = fmaf(H.y, wo[4*j4+1], ac1[e]); \
            ac1[e] = fmaf(H.z, wo[4*j4+2], ac1[e]); \
            ac1[e] = fmaf(H.w, wo[4*j4+3], ac1[e]); \
            ac2[e] = fmaf(H.x, G.x, ac2[e]); \
            ac2[e] = fmaf(H.y, G.y, ac2[e]); \
            ac2[e] = fmaf(H.z, G.z, ac2[e]); \
            ac2[e] = fmaf(H.w, G.w, ac2[e]); \
        } \
    }

__global__ __launch_bounds__(NT)
__attribute__((amdgpu_waves_per_eu(2, 2)))
void ealstm_kernel(
    const float* __restrict__ x_d, const float* __restrict__ x_s,
    const float* __restrict__ W_ih, const float* __restrict__ W_hh,
    const float* __restrict__ W_sh, const float* __restrict__ bias,
    const float* __restrict__ bias_s, const float* __restrict__ W_fc,
    const float* __restrict__ b_fc, float* __restrict__ d_out,
    u32* __restrict__ ws)
{
    extern __shared__ __align__(16) unsigned char smem_raw[];
    Smem& sm = *reinterpret_cast<Smem*>(smem_raw);

    const int t = threadIdx.x;
    const int blk = blockIdx.x;
    const int role = blk >> 6;          // 0..3 : owns units [64*role, +64)
    const int team = blk & 63;          // 0..63: elems {team,+64,+128,+192}
    const int kq8 = t >> 6;             // wave id: consumes h rows [32*kq8,+32)
    const int i   = t & 63;             // lane id
    const int p   = kq8 >> 1;           // role that produces those h rows

    float* __restrict__ out_fc = d_out;                      // [B,S,1]
    float* __restrict__ hn_out = d_out + (size_t)BB * SS;    // [B,S,H]
    float* __restrict__ cn_out = hn_out + (size_t)BB * SS * HH;

    // ws: 64 teams x 4 roles x 16 u32 (64B line) = 16 KB.
    // line: u32[0] = monotone step flag; u32[4..11] = fc partials
    // (2 parity buffers x 4 elems), stored before the flag bump + vmcnt.
    u32* flags   = ws + (size_t)team * 64;
    u32* flag_my = flags + role * 16;

    // ---- register-resident weights: rows [32*kq8,+32) x cols f,o
    float wf[32], wo[32];
    {
        const float* basef = W_hh + (size_t)(32 * kq8) * 768 + 64 * role + i;
#pragma unroll
        for (int j = 0; j < 32; ++j) {
            wf[j] = basef[(size_t)j * 768];
            wo[j] = basef[(size_t)j * 768 + 256];
        }
        // g-gate rows -> LDS float4 (rows 4j4..4j4+3 for col 512+64r+i)
#pragma unroll
        for (int j4 = 0; j4 < 8; ++j4) {
            const float* pg = basef + (size_t)(4 * j4) * 768 + 512;
            sm.wg4[kq8][j4][i] = make_float4(pg[0], pg[768], pg[2 * 768], pg[3 * 768]);
        }
    }
    // ---- W_ih quarter -> LDS
    for (int idx = t; idx < FD * 3 * 64; idx += NT) {
        const int k = idx / 192, rem = idx - k * 192;
        const int g = rem >> 6, cc = rem & 63;
        sm.wih[k][g][cc] = W_ih[(size_t)k * 768 + g * 256 + 64 * role + cc];
    }
    // ---- x row 0 for the 4 elements
    if (t < 128) {
        const int e = t >> 5, xf = t & 31;
        sm.xbuf[0][e][xf] = x_d[(size_t)(team + 64 * e) * SS * FD + xf];
    }
    // ---- gate-lane constants/state (t<256: elem e=t>>6, unit 64*role+(t&63))
    float c_state = 0.f, igv = 0.f, bfv = 0.f, bov = 0.f, bgv = 0.f, wfcv = 0.f;
    if (t < 256) {
        const int e = t >> 6, ii = t & 63, u = 64 * role + ii;
        const int eb = team + 64 * e;
        float accs = bias_s[u];
        for (int k = 0; k < FS; ++k)
            accs = fmaf(x_s[(size_t)eb * FS + k], W_sh[(size_t)k * HH + u], accs);
        igv = 1.f / (1.f + __expf(-accs));
        bfv = bias[u]; bov = bias[HH + u]; bgv = bias[2 * HH + u];
        wfcv = W_fc[u];
        sm.hbuf[e][ii] = 0.f;                      // h0 = 0
    }
    const float bfc = b_fc[0];

    // ---- startup rendezvous through cn_out row 364 (memset pre-launch;
    //      legitimately overwritten only at s=364). Zero own ws flag, drain,
    //      THEN post ready magic -> stale-ws/replay safe. Relaxed atomics.
    u32* rdyrow = (u32*)(cn_out + ((size_t)team * SS + (SS - 1)) * HH);
    if (t == 0) {
        __hip_atomic_store(flag_my, 0u, __ATOMIC_RELAXED, AGENT);
        asm volatile("s_waitcnt vmcnt(0)" ::: "memory");
        __hip_atomic_store(rdyrow + 64 * role, 0x3F800000u, __ATOMIC_RELAXED, AGENT);
        for (int r = 0; r < 4; ++r)
            if (r != role)
                SPIN_UNTIL(__hip_atomic_load(rdyrow + 64 * r, __ATOMIC_RELAXED, AGENT)
                           == 0x3F800000u)
    }
    __syncthreads();

    const size_t ESTR = (size_t)64 * SS * HH;   // elem stride in hn_out
    const u32* hn_u32 = (const u32*)hn_out;

    for (int s = 0; s < SS; ++s) {
        const int par = s & 1;
        // ---- publish step s-1: h rows reached the coherence point at the
        //      end-of-step barrier (vmcnt(0) drain); fc partials into our
        //      flag line, drain, bump monotone flag. All relaxed.
        if (t == 0 && s > 0) {
            const int pp = (s - 1) & 1;
#pragma unroll
            for (int e = 0; e < 4; ++e)
                __hip_atomic_store(flag_my + 4 + pp * 4 + e,
                                   __builtin_bit_cast(u32, sm.outp[e]),
                                   __ATOMIC_RELAXED, AGENT);
            asm volatile("s_waitcnt vmcnt(0)" ::: "memory");
            __hip_atomic_store(flag_my, (u32)s, __ATOMIC_RELAXED, AGENT);
        }
        // ---- x prefetch for s+1 (waves 4-5; lands before the mid barrier)
        float xpre = 0.f; const int xi = t - 256;
        if (xi >= 0 && xi < 128) {
            const int xe = xi >> 5, xf = xi & 31;
            const int sn = (s + 1 < SS) ? s + 1 : SS - 1;
            xpre = x_d[((size_t)(team + 64 * xe) * SS + sn) * FD + xf];
        }
        // ---- x-projection partial (W_ih rows [4*kq8, +4))
        float ac0[4] = {0.f, 0.f, 0.f, 0.f};
        float ac1[4] = {0.f, 0.f, 0.f, 0.f};
        float ac2[4] = {0.f, 0.f, 0.f, 0.f};
        {
            const int x0 = 4 * kq8;
#pragma unroll
            for (int j = 0; j < 4; ++j) {
                const float w0 = sm.wih[x0 + j][0][i];
                const float w1 = sm.wih[x0 + j][1][i];
                const float w2 = sm.wih[x0 + j][2][i];
#pragma unroll
                for (int e = 0; e < 4; ++e) {
                    const float xv = sm.xbuf[par][e][x0 + j];
                    ac0[e] = fmaf(xv, w0, ac0[e]);
                    ac1[e] = fmaf(xv, w1, ac1[e]);
                    ac2[e] = fmaf(xv, w2, ac2[e]);
                }
            }
        }
        // ---- deferred fc head write for s-1 (role 0, wave-4 lane 0)
        if (role == 0 && t == 256 && s > 0) {
            const int pp = (s - 1) & 1;
            for (int r = 1; r < 4; ++r)
                SPIN_UNTIL((int)__hip_atomic_load(flags + r * 16, __ATOMIC_RELAXED,
                                                  AGENT) >= s)
#pragma unroll
            for (int e = 0; e < 4; ++e) {
                float v = sm.outp[e] + bfc;
                for (int r = 1; r < 4; ++r)
                    v += __builtin_bit_cast(float,
                        __hip_atomic_load(flags + r * 16 + 4 + pp * 4 + e,
                                          __ATOMIC_RELAXED, AGENT));
                out_fc[(size_t)(team + 64 * e) * SS + (s - 1)] = v;
            }
        }
        // ---- h @ W_hh (skip at s=0: h=0). Wave-uniform source select.
        if (s > 0) {
            if (p == role) {
                const int hoff = 32 * (kq8 & 1);
                HGEMV(reinterpret_cast<const float4*>(&sm.hbuf[e][hoff])[j4])
            } else {
                SPIN_UNTIL((int)__hip_atomic_load(flags + p * 16, __ATOMIC_RELAXED,
                                                  AGENT) >= s)
                // lane-parallel fetch: 128 partner-h dwords -> LDS bounce
                const size_t base = ((size_t)team * SS + (s - 1)) * HH + 32 * kq8;
#pragma unroll
                for (int half = 0; half < 2; ++half) {
                    const int idx = i + 64 * half;
                    const int e = idx >> 5, r = idx & 31;
                    const u32 v = __hip_atomic_load(
                        hn_u32 + base + (size_t)e * ESTR + r,
                        __ATOMIC_RELAXED, AGENT);
                    sm.hxch[kq8][idx] = __builtin_bit_cast(float, v);
                }
                // same-wave ds_write -> uniform ds_read: lgkmcnt-ordered
                HGEMV(reinterpret_cast<const float4*>(sm.hxch[kq8])[e * 8 + j4])
            }
        }
        // ---- partials + land prefetched x
#pragma unroll
        for (int e = 0; e < 4; ++e) {
            sm.part[e][0][kq8][i] = ac0[e];
            sm.part[e][1][kq8][i] = ac1[e];
            sm.part[e][2][kq8][i] = ac2[e];
        }
        if (xi >= 0 && xi < 128) sm.xbuf[par ^ 1][xi >> 5][xi & 31] = xpre;
        __syncthreads();

        // ---- gate phase (t<256: elem e, unit 64*role+ii)
        if (t < 256) {
            const int e = t >> 6, ii = t & 63;
            float f = bfv, o = bov, g = bgv;
#pragma unroll
            for (int q = 0; q < 8; ++q) {
                f += sm.part[e][0][q][ii];
                o += sm.part[e][1][q][ii];
                g += sm.part[e][2][q][ii];
            }
            const float sf = 1.f / (1.f + __expf(-f));
            const float so = 1.f / (1.f + __expf(-o));
            const float tg = 1.f - 2.f / (1.f + __expf(2.f * g));   // safe tanh
            c_state = sf * c_state + igv * tg;
            const float tc = 1.f - 2.f / (1.f + __expf(2.f * c_state));
            const float h1 = so * tc;
            sm.hbuf[e][ii] = h1;
            const size_t oidx = ((size_t)(team + 64 * e) * SS + s) * HH + 64 * role + ii;
            // h visible at the device coherence point (partner reads it)
            __hip_atomic_store((u32*)hn_out + oidx, __builtin_bit_cast(u32, h1),
                               __ATOMIC_RELAXED, AGENT);
            cn_out[oidx] = c_state;   // not read cross-CU: normal store
            float psum = h1 * wfcv;
#pragma unroll
            for (int d = 32; d > 0; d >>= 1) psum += __shfl_down(psum, d);
            if (ii == 0) sm.outp[e] = psum;
        }
        __syncthreads();   // vmcnt(0) drain: h stores committed before publish
    }

    // ---- epilogue: final publish + fc row 364
    {
        const int pp = (SS - 1) & 1;
        if (t == 0) {
#pragma unroll
            for (int e = 0; e < 4; ++e)
                __hip_atomic_store(flag_my + 4 + pp * 4 + e,
                                   __builtin_bit_cast(u32, sm.outp[e]),
                                   __ATOMIC_RELAXED, AGENT);
            asm volatile("s_waitcnt vmcnt(0)" ::: "memory");
            __hip_atomic_store(flag_my, (u32)SS, __ATOMIC_RELAXED, AGENT);
        }
        if (role == 0 && t == 256) {
            for (int r = 1; r < 4; ++r)
                SPIN_UNTIL((int)__hip_atomic_load(flags + r * 16, __ATOMIC_RELAXED,
                                                  AGENT) >= SS)
#pragma unroll
            for (int e = 0; e < 4; ++e) {
                float v = sm.outp[e] + bfc;
                for (int r = 1; r < 4; ++r)
                    v += __builtin_bit_cast(float,
                        __hip_atomic_load(flags + r * 16 + 4 + pp * 4 + e,
                                          __ATOMIC_RELAXED, AGENT));
                out_fc[(size_t)(team + 64 * e) * SS + (SS - 1)] = v;
            }
        }
    }
}

extern "C" void kernel_launch(void* const* d_in, const int* in_sizes, int n_in,
                              void* d_out, int out_size, void* d_ws, size_t ws_size,
                              hipStream_t stream) {
    const float* x_d    = (const float*)d_in[0];
    const float* x_s    = (const float*)d_in[1];
    const float* W_ih   = (const float*)d_in[2];
    const float* W_hh   = (const float*)d_in[3];
    const float* W_sh   = (const float*)d_in[4];
    const float* bias   = (const float*)d_in[5];
    const float* bias_s = (const float*)d_in[6];
    const float* W_fc   = (const float*)d_in[7];
    const float* b_fc   = (const float*)d_in[8];

    static bool smem_set = false;
    if (!smem_set) {
        hipFuncSetAttribute((const void*)ealstm_kernel,
                            hipFuncAttributeMaxDynamicSharedMemorySize,
                            (int)sizeof(Smem));
        smem_set = true;
    }

    ealstm_kernel<<<dim3(BB), dim3(NT), sizeof(Smem), stream>>>(
        x_d, x_s, W_ih, W_hh, W_sh, bias, bias_s, W_fc, b_fc,
        (float*)d_out, (u32*)d_ws);
}

// Round 8
// 8388.505 us; speedup vs baseline: 2.2190x; 1.0225x over previous
//
#include <hip/hip_runtime.h>

// EA-LSTM fused kernel, v8: full fp32, 4-CU teams, spill-proof registers.
//
// v7 post-mortem: FETCH/block-step = 126 KB == wf+wo bytes; VGPR_Count
// pinned EXACTLY at the 128 cap; runtime == FETCH/1.45TB/s. Diagnosis:
// RA pressure > cap -> wf/wo spilled to scratch; scratch's swizzled
// per-thread mapping defeats L2/L3 -> re-streamed from HBM all 365 steps.
// Every version v4-v7 allocated at its cap and paid HBM for the overflow.
//
// v8 fixes the register budget itself:
//  - no __launch_bounds__; amdgpu_flat_work_group_size(512,512) +
//    amdgpu_waves_per_eu(1,2): min-1-wave/EU legalizes up to 512 VGPRs,
//    so the ~100-reg ask cannot spill. (LDS 118 KB already limits us to
//    1 block/CU = 2 waves/SIMD; we give the allocator that truth.)
//  - wf/wo laundered through asm("":"+v") right after load: no longer
//    rematerializable-invariant loads, must stay in VGPRs.
//  - flag polls: lane 0 only + __shfl broadcast (64x less poll traffic).
//
// Layout/protocol byte-identical to v7 (passed twice at absmax 0.5):
// 64 teams x 4 roles; block = role*64+team; partners {team,+64,+128,+192}
// same XCD. Role owns 64 output units (cols {64r+i,256+64r+i,512+64r+i}).
// Thread (kq8=t>>6, i=t&63) holds rows [32*kq8,+32) x f,o cols in regs;
// g-gate weights in LDS (64 KB), W_ih quarter (24 KB), partials (24 KB),
// h-exchange bounce (4 KB). Team processes 4 batch elements.
// Cross-CU h via relaxed agent atomics through hn_out (output anyway) +
// monotone step flag in d_ws; __syncthreads()' vmcnt(0) drain = release
// ordering. Startup rendezvous through cn_out row 364 (memset pre-launch,
// legitimately overwritten only at s=364) -> stale-ws/replay safe.

#define BB 256
#define SS 365
#define FD 32
#define FS 27
#define HH 256
#define NT 512
typedef unsigned int u32;

#define AGENT __HIP_MEMORY_SCOPE_AGENT

// scalar-context bounded spin (single lane executes it)
#define SPIN_UNTIL(COND) \
    { int _it = 0; while (!(COND) && _it < (1 << 26)) { __builtin_amdgcn_s_sleep(2); ++_it; } \
      asm volatile("" ::: "memory"); }

// wave-wide bounded wait: lane 0 polls, all lanes get the value via shfl.
__device__ __forceinline__ void wave_wait_ge(u32* addr, int target, int lane) {
    for (int it = 0; it < (1 << 26); ++it) {
        u32 f = (lane == 0) ? __hip_atomic_load(addr, __ATOMIC_RELAXED, AGENT) : 0u;
        f = (u32)__shfl((int)f, 0);
        if ((int)f >= target) break;
        __builtin_amdgcn_s_sleep(2);
    }
    asm volatile("" ::: "memory");
}

struct Smem {
    __align__(16) float4 wg4[8][8][64];    // 64 KB  g-gate weights [kq8][j4][i]
    __align__(16) float wih[FD][3][64];    // 24 KB  W_ih quarter
    __align__(16) float part[4][3][8][64]; // 24 KB  partials [elem][gate][kq8][i]
    __align__(16) float hbuf[4][64];       // 1 KB   own-slice h per elem
    __align__(16) float hxch[8][128];      // 4 KB   per-wave partner-h bounce
    __align__(16) float xbuf[2][4][FD];    // 1 KB   x rows, double-buffered
    float outp[4];                         // per-elem fc wave sums
};

// 4 rows x 3 gates x 4 elems of MACs; wf/wo from regs, g from LDS float4.
#define HGEMV(SRC) \
    _Pragma("unroll") \
    for (int j4 = 0; j4 < 8; ++j4) { \
        const float4 G = sm.wg4[kq8][j4][i]; \
        _Pragma("unroll") \
        for (int e = 0; e < 4; ++e) { \
            const float4 H = (SRC); \
            ac0[e] = fmaf(H.x, wf[4*j4+0], ac0[e]); \
            ac0[e] = fmaf(H.y, wf[4*j4+1], ac0[e]); \
            ac0[e] = fmaf(H.z, wf[4*j4+2], ac0[e]); \
            ac0[e] = fmaf(H.w, wf[4*j4+3], ac0[e]); \
            ac1[e] = fmaf(H.x, wo[4*j4+0], ac1[e]); \
            ac1[e] = fmaf(H.y, wo[4*j4+1], ac1[e]); \
            ac1[e] = fmaf(H.z, wo[4*j4+2], ac1[e]); \
            ac1[e] = fmaf(H.w, wo[4*j4+3], ac1[e]); \
            ac2[e] = fmaf(H.x, G.x, ac2[e]); \
            ac2[e] = fmaf(H.y, G.y, ac2[e]); \
            ac2[e] = fmaf(H.z, G.z, ac2[e]); \
            ac2[e] = fmaf(H.w, G.w, ac2[e]); \
        } \
    }

__global__
__attribute__((amdgpu_flat_work_group_size(512, 512)))
__attribute__((amdgpu_waves_per_eu(1, 2)))
void ealstm_kernel(
    const float* __restrict__ x_d, const float* __restrict__ x_s,
    const float* __restrict__ W_ih, const float* __restrict__ W_hh,
    const float* __restrict__ W_sh, const float* __restrict__ bias,
    const float* __restrict__ bias_s, const float* __restrict__ W_fc,
    const float* __restrict__ b_fc, float* __restrict__ d_out,
    u32* __restrict__ ws)
{
    extern __shared__ __align__(16) unsigned char smem_raw[];
    Smem& sm = *reinterpret_cast<Smem*>(smem_raw);

    const int t = threadIdx.x;
    const int blk = blockIdx.x;
    const int role = blk >> 6;          // 0..3 : owns units [64*role, +64)
    const int team = blk & 63;          // 0..63: elems {team,+64,+128,+192}
    const int kq8 = t >> 6;             // wave id: consumes h rows [32*kq8,+32)
    const int i   = t & 63;             // lane id
    const int p   = kq8 >> 1;           // role that produces those h rows

    float* __restrict__ out_fc = d_out;                      // [B,S,1]
    float* __restrict__ hn_out = d_out + (size_t)BB * SS;    // [B,S,H]
    float* __restrict__ cn_out = hn_out + (size_t)BB * SS * HH;

    // ws: 64 teams x 4 roles x 16 u32 (64B line) = 16 KB.
    // line: u32[0] = monotone step flag; u32[4..11] = fc partials
    // (2 parity buffers x 4 elems), stored before the flag bump + vmcnt.
    u32* flags   = ws + (size_t)team * 64;
    u32* flag_my = flags + role * 16;

    // ---- register-resident weights: rows [32*kq8,+32) x cols f,o
    float wf[32], wo[32];
    {
        const float* basef = W_hh + (size_t)(32 * kq8) * 768 + 64 * role + i;
#pragma unroll
        for (int j = 0; j < 32; ++j) {
            wf[j] = basef[(size_t)j * 768];
            wo[j] = basef[(size_t)j * 768 + 256];
        }
        // launder: opaque register values -> cannot be rematerialized
        // from memory; with the 1-wave/EU budget they cannot spill either.
#pragma unroll
        for (int j = 0; j < 32; ++j)
            asm volatile("" : "+v"(wf[j]), "+v"(wo[j]));
        // g-gate rows -> LDS float4 (rows 4j4..4j4+3 for col 512+64r+i)
#pragma unroll
        for (int j4 = 0; j4 < 8; ++j4) {
            const float* pg = basef + (size_t)(4 * j4) * 768 + 512;
            sm.wg4[kq8][j4][i] = make_float4(pg[0], pg[768], pg[2 * 768], pg[3 * 768]);
        }
    }
    // ---- W_ih quarter -> LDS
    for (int idx = t; idx < FD * 3 * 64; idx += NT) {
        const int k = idx / 192, rem = idx - k * 192;
        const int g = rem >> 6, cc = rem & 63;
        sm.wih[k][g][cc] = W_ih[(size_t)k * 768 + g * 256 + 64 * role + cc];
    }
    // ---- x row 0 for the 4 elements
    if (t < 128) {
        const int e = t >> 5, xf = t & 31;
        sm.xbuf[0][e][xf] = x_d[(size_t)(team + 64 * e) * SS * FD + xf];
    }
    // ---- gate-lane constants/state (t<256: elem e=t>>6, unit 64*role+(t&63))
    float c_state = 0.f, igv = 0.f, bfv = 0.f, bov = 0.f, bgv = 0.f, wfcv = 0.f;
    if (t < 256) {
        const int e = t >> 6, ii = t & 63, u = 64 * role + ii;
        const int eb = team + 64 * e;
        float accs = bias_s[u];
        for (int k = 0; k < FS; ++k)
            accs = fmaf(x_s[(size_t)eb * FS + k], W_sh[(size_t)k * HH + u], accs);
        igv = 1.f / (1.f + __expf(-accs));
        bfv = bias[u]; bov = bias[HH + u]; bgv = bias[2 * HH + u];
        wfcv = W_fc[u];
        sm.hbuf[e][ii] = 0.f;                      // h0 = 0
    }
    const float bfc = b_fc[0];

    // ---- startup rendezvous through cn_out row 364 (memset pre-launch;
    //      legitimately overwritten only at s=364). Zero own ws flag, drain,
    //      THEN post ready magic -> stale-ws/replay safe. Relaxed atomics.
    u32* rdyrow = (u32*)(cn_out + ((size_t)team * SS + (SS - 1)) * HH);
    if (t == 0) {
        __hip_atomic_store(flag_my, 0u, __ATOMIC_RELAXED, AGENT);
        asm volatile("s_waitcnt vmcnt(0)" ::: "memory");
        __hip_atomic_store(rdyrow + 64 * role, 0x3F800000u, __ATOMIC_RELAXED, AGENT);
        for (int r = 0; r < 4; ++r)
            if (r != role)
                SPIN_UNTIL(__hip_atomic_load(rdyrow + 64 * r, __ATOMIC_RELAXED, AGENT)
                           == 0x3F800000u)
    }
    __syncthreads();

    const size_t ESTR = (size_t)64 * SS * HH;   // elem stride in hn_out
    const u32* hn_u32 = (const u32*)hn_out;

    for (int s = 0; s < SS; ++s) {
        const int par = s & 1;
        // ---- publish step s-1: h rows reached the coherence point at the
        //      end-of-step barrier (vmcnt(0) drain); fc partials into our
        //      flag line, drain, bump monotone flag. All relaxed.
        if (t == 0 && s > 0) {
            const int pp = (s - 1) & 1;
#pragma unroll
            for (int e = 0; e < 4; ++e)
                __hip_atomic_store(flag_my + 4 + pp * 4 + e,
                                   __builtin_bit_cast(u32, sm.outp[e]),
                                   __ATOMIC_RELAXED, AGENT);
            asm volatile("s_waitcnt vmcnt(0)" ::: "memory");
            __hip_atomic_store(flag_my, (u32)s, __ATOMIC_RELAXED, AGENT);
        }
        // ---- x prefetch for s+1 (waves 4-5; lands before the mid barrier)
        float xpre = 0.f; const int xi = t - 256;
        if (xi >= 0 && xi < 128) {
            const int xe = xi >> 5, xf = xi & 31;
            const int sn = (s + 1 < SS) ? s + 1 : SS - 1;
            xpre = x_d[((size_t)(team + 64 * xe) * SS + sn) * FD + xf];
        }
        // ---- x-projection partial (W_ih rows [4*kq8, +4))
        float ac0[4] = {0.f, 0.f, 0.f, 0.f};
        float ac1[4] = {0.f, 0.f, 0.f, 0.f};
        float ac2[4] = {0.f, 0.f, 0.f, 0.f};
        {
            const int x0 = 4 * kq8;
#pragma unroll
            for (int j = 0; j < 4; ++j) {
                const float w0 = sm.wih[x0 + j][0][i];
                const float w1 = sm.wih[x0 + j][1][i];
                const float w2 = sm.wih[x0 + j][2][i];
#pragma unroll
                for (int e = 0; e < 4; ++e) {
                    const float xv = sm.xbuf[par][e][x0 + j];
                    ac0[e] = fmaf(xv, w0, ac0[e]);
                    ac1[e] = fmaf(xv, w1, ac1[e]);
                    ac2[e] = fmaf(xv, w2, ac2[e]);
                }
            }
        }
        // ---- deferred fc head write for s-1 (role 0, wave-4 lane 0)
        if (role == 0 && t == 256 && s > 0) {
            const int pp = (s - 1) & 1;
            for (int r = 1; r < 4; ++r)
                SPIN_UNTIL((int)__hip_atomic_load(flags + r * 16, __ATOMIC_RELAXED,
                                                  AGENT) >= s)
#pragma unroll
            for (int e = 0; e < 4; ++e) {
                float v = sm.outp[e] + bfc;
                for (int r = 1; r < 4; ++r)
                    v += __builtin_bit_cast(float,
                        __hip_atomic_load(flags + r * 16 + 4 + pp * 4 + e,
                                          __ATOMIC_RELAXED, AGENT));
                out_fc[(size_t)(team + 64 * e) * SS + (s - 1)] = v;
            }
        }
        // ---- h @ W_hh (skip at s=0: h=0). Wave-uniform source select.
        if (s > 0) {
            if (p == role) {
                const int hoff = 32 * (kq8 & 1);
                HGEMV(reinterpret_cast<const float4*>(&sm.hbuf[e][hoff])[j4])
            } else {
                wave_wait_ge(flags + p * 16, s, i);
                // lane-parallel fetch: 128 partner-h dwords -> LDS bounce
                const size_t base = ((size_t)team * SS + (s - 1)) * HH + 32 * kq8;
#pragma unroll
                for (int half = 0; half < 2; ++half) {
                    const int idx = i + 64 * half;
                    const int e = idx >> 5, r = idx & 31;
                    const u32 v = __hip_atomic_load(
                        hn_u32 + base + (size_t)e * ESTR + r,
                        __ATOMIC_RELAXED, AGENT);
                    sm.hxch[kq8][idx] = __builtin_bit_cast(float, v);
                }
                // same-wave ds_write -> uniform ds_read: lgkmcnt-ordered
                HGEMV(reinterpret_cast<const float4*>(sm.hxch[kq8])[e * 8 + j4])
            }
        }
        // ---- partials + land prefetched x
#pragma unroll
        for (int e = 0; e < 4; ++e) {
            sm.part[e][0][kq8][i] = ac0[e];
            sm.part[e][1][kq8][i] = ac1[e];
            sm.part[e][2][kq8][i] = ac2[e];
        }
        if (xi >= 0 && xi < 128) sm.xbuf[par ^ 1][xi >> 5][xi & 31] = xpre;
        __syncthreads();

        // ---- gate phase (t<256: elem e, unit 64*role+ii)
        if (t < 256) {
            const int e = t >> 6, ii = t & 63;
            float f = bfv, o = bov, g = bgv;
#pragma unroll
            for (int q = 0; q < 8; ++q) {
                f += sm.part[e][0][q][ii];
                o += sm.part[e][1][q][ii];
                g += sm.part[e][2][q][ii];
            }
            const float sf = 1.f / (1.f + __expf(-f));
            const float so = 1.f / (1.f + __expf(-o));
            const float tg = 1.f - 2.f / (1.f + __expf(2.f * g));   // safe tanh
            c_state = sf * c_state + igv * tg;
            const float tc = 1.f - 2.f / (1.f + __expf(2.f * c_state));
            const float h1 = so * tc;
            sm.hbuf[e][ii] = h1;
            const size_t oidx = ((size_t)(team + 64 * e) * SS + s) * HH + 64 * role + ii;
            // h visible at the device coherence point (partner reads it)
            __hip_atomic_store((u32*)hn_out + oidx, __builtin_bit_cast(u32, h1),
                               __ATOMIC_RELAXED, AGENT);
            cn_out[oidx] = c_state;   // not read cross-CU: normal store
            float psum = h1 * wfcv;
#pragma unroll
            for (int d = 32; d > 0; d >>= 1) psum += __shfl_down(psum, d);
            if (ii == 0) sm.outp[e] = psum;
        }
        __syncthreads();   // vmcnt(0) drain: h stores committed before publish
    }

    // ---- epilogue: final publish + fc row 364
    {
        const int pp = (SS - 1) & 1;
        if (t == 0) {
#pragma unroll
            for (int e = 0; e < 4; ++e)
                __hip_atomic_store(flag_my + 4 + pp * 4 + e,
                                   __builtin_bit_cast(u32, sm.outp[e]),
                                   __ATOMIC_RELAXED, AGENT);
            asm volatile("s_waitcnt vmcnt(0)" ::: "memory");
            __hip_atomic_store(flag_my, (u32)SS, __ATOMIC_RELAXED, AGENT);
        }
        if (role == 0 && t == 256) {
            for (int r = 1; r < 4; ++r)
                SPIN_UNTIL((int)__hip_atomic_load(flags + r * 16, __ATOMIC_RELAXED,
                                                  AGENT) >= SS)
#pragma unroll
            for (int e = 0; e < 4; ++e) {
                float v = sm.outp[e] + bfc;
                for (int r = 1; r < 4; ++r)
                    v += __builtin_bit_cast(float,
                        __hip_atomic_load(flags + r * 16 + 4 + pp * 4 + e,
                                          __ATOMIC_RELAXED, AGENT));
                out_fc[(size_t)(team + 64 * e) * SS + (SS - 1)] = v;
            }
        }
    }
}

extern "C" void kernel_launch(void* const* d_in, const int* in_sizes, int n_in,
                              void* d_out, int out_size, void* d_ws, size_t ws_size,
                              hipStream_t stream) {
    const float* x_d    = (const float*)d_in[0];
    const float* x_s    = (const float*)d_in[1];
    const float* W_ih   = (const float*)d_in[2];
    const float* W_hh   = (const float*)d_in[3];
    const float* W_sh   = (const float*)d_in[4];
    const float* bias   = (const float*)d_in[5];
    const float* bias_s = (const float*)d_in[6];
    const float* W_fc   = (const float*)d_in[7];
    const float* b_fc   = (const float*)d_in[8];

    static bool smem_set = false;
    if (!smem_set) {
        hipFuncSetAttribute((const void*)ealstm_kernel,
                            hipFuncAttributeMaxDynamicSharedMemorySize,
                            (int)sizeof(Smem));
        smem_set = true;
    }

    ealstm_kernel<<<dim3(BB), dim3(NT), sizeof(Smem), stream>>>(
        x_d, x_s, W_ih, W_hh, W_sh, bias, bias_s, W_fc, b_fc,
        (float*)d_out, (u32*)d_ws);
}